// Round 1
// baseline (3735.861 us; speedup 1.0000x reference)
//
#include <hip/hip_runtime.h>
#include <math.h>

// Shapes (fixed for this problem)
#define BB 8
#define SEQ 2049
#define NT 2048      // tokens after cls
#define DD 1024
#define EE 8
#define SS 256
#define ESN 2048     // E*S
#define HH 512
#define NCH 16       // col-softmax row chunks

__device__ __forceinline__ float gelu_f(float v) {
  return 0.5f * v * (1.0f + erff(v * 0.70710678118654752440f));
}

__device__ __forceinline__ float wave_sum(float v) {
#pragma unroll
  for (int off = 1; off < 64; off <<= 1) v += __shfl_xor(v, off);
  return v;
}
__device__ __forceinline__ float wave_max(float v) {
#pragma unroll
  for (int off = 1; off < 64; off <<= 1) v = fmaxf(v, __shfl_xor(v, off));
  return v;
}

// Shared 64x64x16 f32 tile inner product. as/bs are kk-major [16][68]
// (pad 68 -> fragment reads are 16B-aligned ds_read_b128, <=2-way banks).
__device__ __forceinline__ void tile_fma(const float (*as)[68], const float (*bs)[68],
                                         float acc[4][4], int tx, int ty) {
#pragma unroll
  for (int kk = 0; kk < 16; ++kk) {
    float ar[4], br[4];
#pragma unroll
    for (int i = 0; i < 4; ++i) ar[i] = as[kk][ty * 4 + i];
#pragma unroll
    for (int j = 0; j < 4; ++j) br[j] = bs[kk][tx * 4 + j];
#pragma unroll
    for (int i = 0; i < 4; ++i)
#pragma unroll
      for (int j = 0; j < 4; ++j) acc[i][j] = fmaf(ar[i], br[j], acc[i][j]);
  }
}

// -------- cls path --------
__global__ __launch_bounds__(256) void k_clsA(const float* __restrict__ x,
    const float* __restrict__ w1, const float* __restrict__ b1, float* __restrict__ clsh) {
  const int wid = blockIdx.x * 4 + (threadIdx.x >> 6);
  const int lane = threadIdx.x & 63;
  const int b = wid >> 9, h = wid & (HH - 1);
  const float* xr = x + (size_t)b * SEQ * DD;  // row 0
  const float* wr = w1 + (size_t)h * DD;
  float s = 0.f;
#pragma unroll
  for (int k = 0; k < DD / 64; ++k) s = fmaf(xr[lane + k * 64], wr[lane + k * 64], s);
  s = wave_sum(s);
  if (lane == 0) clsh[wid] = gelu_f(s + b1[h]);
}

__global__ __launch_bounds__(256) void k_clsB(const float* __restrict__ clsh,
    const float* __restrict__ w2, const float* __restrict__ b2, float* __restrict__ out) {
  const int wid = blockIdx.x * 4 + (threadIdx.x >> 6);
  const int lane = threadIdx.x & 63;
  const int b = wid >> 10, d = wid & (DD - 1);
  const float* hr = clsh + (size_t)b * HH;
  const float* wr = w2 + (size_t)d * HH;
  float s = 0.f;
#pragma unroll
  for (int k = 0; k < HH / 64; ++k) s = fmaf(hr[lane + k * 64], wr[lane + k * 64], s);
  s = wave_sum(s);
  if (lane == 0) out[(size_t)b * SEQ * DD + d] = s + b2[d];
}

// -------- normalization factors --------
__global__ __launch_bounds__(256) void k_xnf(const float* __restrict__ x, float* __restrict__ xnf) {
  const int wid = blockIdx.x * 4 + (threadIdx.x >> 6);  // b*NT + n
  const int lane = threadIdx.x & 63;
  const int b = wid >> 11, n = wid & (NT - 1);
  const float* row = x + ((size_t)b * SEQ + 1 + n) * DD;
  float s = 0.f;
#pragma unroll
  for (int k = 0; k < DD / 64; ++k) { const float v = row[lane + k * 64]; s = fmaf(v, v, s); }
  s = wave_sum(s);
  if (lane == 0) xnf[wid] = 1.0f / fmaxf(sqrtf(s), 1e-12f);
}

__global__ __launch_bounds__(256) void k_munf(const float* __restrict__ mu,
    const float* __restrict__ scale, float* __restrict__ munf) {
  const int c = blockIdx.x * 256 + threadIdx.x;  // thread per column: coalesced over c
  float s = 0.f;
  for (int d = 0; d < DD; ++d) { const float v = mu[(size_t)d * ESN + c]; s = fmaf(v, v, s); }
  munf[c] = scale[0] / fmaxf(sqrtf(s), 1e-12f);
}

// -------- logits = (xnf*xt) @ (munf*mu)  -> L[b][n][c] --------
__global__ __launch_bounds__(256) void k_logits(const float* __restrict__ x,
    const float* __restrict__ mu, const float* __restrict__ xnf,
    const float* __restrict__ munf, float* __restrict__ L) {
  __shared__ float as[16][68], bs[16][68];
  const int b = blockIdx.z;
  const int n0 = blockIdx.x * 64, c0 = blockIdx.y * 64;
  const int t = threadIdx.x, tx = t & 15, ty = t >> 4;
  const float* A = x + ((size_t)b * SEQ + 1) * DD;
  const int ak = t & 15, ar = t >> 4;
  const int bc = t & 63, bk = t >> 6;
  float acc[4][4] = {};
  for (int k0 = 0; k0 < DD; k0 += 16) {
#pragma unroll
    for (int j = 0; j < 4; ++j)
      as[ak][ar + 16 * j] = A[(size_t)(n0 + ar + 16 * j) * DD + k0 + ak];
#pragma unroll
    for (int j = 0; j < 4; ++j)
      bs[bk + 4 * j][bc] = mu[(size_t)(k0 + bk + 4 * j) * ESN + c0 + bc];
    __syncthreads();
    tile_fma(as, bs, acc, tx, ty);
    __syncthreads();
  }
#pragma unroll
  for (int i = 0; i < 4; ++i) {
    const int n = n0 + ty * 4 + i;
    const float xs = xnf[b * NT + n];
#pragma unroll
    for (int j = 0; j < 4; ++j) {
      const int c = c0 + tx * 4 + j;
      L[((size_t)b * NT + n) * ESN + c] = acc[i][j] * xs * munf[c];
    }
  }
}

// -------- row softmax stats (combine) + m1 per-row terms --------
__global__ __launch_bounds__(256) void k_rowstats(const float* __restrict__ L,
    float* __restrict__ rmax, float* __restrict__ rinv,
    float* __restrict__ t_r2, float* __restrict__ t_dr) {
  const int wid = blockIdx.x * 4 + (threadIdx.x >> 6);  // b*NT + n
  const int lane = threadIdx.x & 63;
  const int n = wid & (NT - 1);
  const float* row = L + (size_t)wid * ESN;
  float v[32];
  float m = -INFINITY;
#pragma unroll
  for (int k = 0; k < 32; ++k) { v[k] = row[lane + k * 64]; m = fmaxf(m, v[k]); }
  m = wave_max(m);
  float s1 = 0.f, s2 = 0.f;
#pragma unroll
  for (int k = 0; k < 32; ++k) { const float e = expf(v[k] - m); s1 += e; s2 += e * e; }
  s1 = wave_sum(s1);
  s2 = wave_sum(s2);
  if (lane == 0) {
    rmax[wid] = m;
    rinv[wid] = 1.0f / s1;
    const float q = s2 / (s1 * s1);        // sum combine^2
    const float r2 = 1.0f / (q + 1e-9f);   // r^2, r = rsqrt(q+1e-9)
    t_r2[wid] = r2;
    const float cd = expf(row[n] - m) / s1;  // combine[b,n,n]
    t_dr[wid] = cd * r2;                      // diag*r = cd*r * r
  }
}

// -------- col softmax stats (dispatch), two-phase online --------
__global__ __launch_bounds__(256) void k_colpart(const float* __restrict__ L,
    float* __restrict__ pm, float* __restrict__ ps, float* __restrict__ pq) {
  const int b = blockIdx.x, cb = blockIdx.y, nch = blockIdx.z;
  const int c = cb * 256 + threadIdx.x;
  const float* base = L + ((size_t)b * NT + nch * (NT / NCH)) * ESN + c;
  float m = -INFINITY, s = 0.f, sq = 0.f;
  for (int i = 0; i < NT / NCH; ++i) {
    const float v = base[(size_t)i * ESN];
    const float nm = fmaxf(m, v);
    const float sc = expf(m - nm);   // first iter: expf(-inf)=0
    const float ev = expf(v - nm);
    s = s * sc + ev;
    sq = sq * sc * sc + ev * ev;
    m = nm;
  }
  const int idx = (nch * BB + b) * ESN + c;  // [nch][b][c] -> merge reads coalesced
  pm[idx] = m; ps[idx] = s; pq[idx] = sq;
}

__global__ __launch_bounds__(256) void k_colmerge(const float* __restrict__ pm,
    const float* __restrict__ ps, const float* __restrict__ pq,
    float* __restrict__ cmax, float* __restrict__ cinv,
    float* __restrict__ t_rs2, float* __restrict__ t_sd) {
  const int gid = blockIdx.x * 256 + threadIdx.x;  // b*ESN + c
  float m = -INFINITY;
#pragma unroll
  for (int k = 0; k < NCH; ++k) m = fmaxf(m, pm[k * (BB * ESN) + gid]);
  float s = 0.f, sq = 0.f;
#pragma unroll
  for (int k = 0; k < NCH; ++k) {
    const float d = expf(pm[k * (BB * ESN) + gid] - m);
    s += ps[k * (BB * ESN) + gid] * d;
    sq += pq[k * (BB * ESN) + gid] * d * d;
  }
  cmax[gid] = m;
  cinv[gid] = 1.0f / s;
  const float q2 = sq / (s * s);
  const float rs2 = 1.0f / (q2 + 1e-9f);
  t_rs2[gid] = rs2;
  const int c = gid & (ESN - 1);
  // diag (e=i,s=i): c = i*257, i<8 -> {0,257,...,1799}
  t_sd[gid] = ((c % 257) == 0) ? rs2 : 0.f;
}

// -------- slot_in[c][d] = sum_n dispatch[n][c] * xt[n][d] --------
__global__ __launch_bounds__(256) void k_slot_in(const float* __restrict__ L,
    const float* __restrict__ x, const float* __restrict__ cmax,
    const float* __restrict__ cinv, float* __restrict__ SI) {
  __shared__ float as[16][68], bs[16][68];
  const int b = blockIdx.z;
  const int c0 = blockIdx.x * 64, d0 = blockIdx.y * 64;
  const int t = threadIdx.x, tx = t & 15, ty = t >> 4;
  const float* Lb = L + (size_t)b * NT * ESN;
  const float* Xb = x + ((size_t)b * SEQ + 1) * DD;
  const int lc = t & 63, ln = t >> 6;
  const float cm = cmax[b * ESN + c0 + lc];
  float acc[4][4] = {};
  for (int n0 = 0; n0 < NT; n0 += 16) {
#pragma unroll
    for (int j = 0; j < 4; ++j) {
      const int nn = ln + 4 * j;
      as[nn][lc] = expf(Lb[(size_t)(n0 + nn) * ESN + c0 + lc] - cm);  // transposed into [n][c]
    }
#pragma unroll
    for (int j = 0; j < 4; ++j) {
      const int nn = ln + 4 * j;
      bs[nn][lc] = Xb[(size_t)(n0 + nn) * DD + d0 + lc];
    }
    __syncthreads();
    tile_fma(as, bs, acc, tx, ty);
    __syncthreads();
  }
#pragma unroll
  for (int i = 0; i < 4; ++i) {
    const int c = c0 + ty * 4 + i;
    const float ci = cinv[b * ESN + c];
#pragma unroll
    for (int j = 0; j < 4; ++j)
      SI[((size_t)b * ESN + c) * DD + d0 + tx * 4 + j] = acc[i][j] * ci;
  }
}

// -------- expert FFN layer 1: H1 = gelu(SI @ w1[e]^T + b1[e]) --------
__global__ __launch_bounds__(256) void k_ffn1(const float* __restrict__ SI,
    const float* __restrict__ w1, const float* __restrict__ b1, float* __restrict__ H1) {
  __shared__ float as[16][68], bs[16][68];
  const int be = blockIdx.z, b = be >> 3, e = be & 7;
  const int s0 = blockIdx.x * 64, h0 = blockIdx.y * 64;
  const int t = threadIdx.x, tx = t & 15, ty = t >> 4;
  const float* A = SI + ((size_t)b * ESN + e * SS) * DD;
  const float* Bm = w1 + (size_t)e * HH * DD;
  const int ak = t & 15, ar = t >> 4;
  const int bd = t & 15, bh = t >> 4;
  float acc[4][4] = {};
  for (int k0 = 0; k0 < DD; k0 += 16) {
#pragma unroll
    for (int j = 0; j < 4; ++j)
      as[ak][ar + 16 * j] = A[(size_t)(s0 + ar + 16 * j) * DD + k0 + ak];
#pragma unroll
    for (int j = 0; j < 4; ++j)
      bs[bd][bh + 16 * j] = Bm[(size_t)(h0 + bh + 16 * j) * DD + k0 + bd];
    __syncthreads();
    tile_fma(as, bs, acc, tx, ty);
    __syncthreads();
  }
#pragma unroll
  for (int i = 0; i < 4; ++i) {
    const int s = s0 + ty * 4 + i;
#pragma unroll
    for (int j = 0; j < 4; ++j) {
      const int h = h0 + tx * 4 + j;
      H1[((size_t)(b * EE + e) * SS + s) * HH + h] = gelu_f(acc[i][j] + b1[e * HH + h]);
    }
  }
}

// -------- expert FFN layer 2: SO = H1 @ w2[e]^T + b2[e] --------
__global__ __launch_bounds__(256) void k_ffn2(const float* __restrict__ H1,
    const float* __restrict__ w2, const float* __restrict__ b2, float* __restrict__ SO) {
  __shared__ float as[16][68], bs[16][68];
  const int be = blockIdx.z, b = be >> 3, e = be & 7;
  const int s0 = blockIdx.x * 64, d0 = blockIdx.y * 64;
  const int t = threadIdx.x, tx = t & 15, ty = t >> 4;
  const float* A = H1 + (size_t)(b * EE + e) * SS * HH;
  const float* Bm = w2 + (size_t)e * DD * HH;
  const int ak = t & 15, ar = t >> 4;
  const int bh = t & 15, bd = t >> 4;
  float acc[4][4] = {};
  for (int k0 = 0; k0 < HH; k0 += 16) {
#pragma unroll
    for (int j = 0; j < 4; ++j)
      as[ak][ar + 16 * j] = A[(size_t)(s0 + ar + 16 * j) * HH + k0 + ak];
#pragma unroll
    for (int j = 0; j < 4; ++j)
      bs[bh][bd + 16 * j] = Bm[(size_t)(d0 + bd + 16 * j) * HH + k0 + bh];
    __syncthreads();
    tile_fma(as, bs, acc, tx, ty);
    __syncthreads();
  }
#pragma unroll
  for (int i = 0; i < 4; ++i) {
    const int s = s0 + ty * 4 + i;
#pragma unroll
    for (int j = 0; j < 4; ++j) {
      const int d = d0 + tx * 4 + j;
      SO[((size_t)b * ESN + e * SS + s) * DD + d] = acc[i][j] + b2[e * DD + d];
    }
  }
}

// -------- img[n][d] = sum_c combine[n][c] * SO[c][d]  (writes rows 1.. of out) --------
__global__ __launch_bounds__(256) void k_img(const float* __restrict__ L,
    const float* __restrict__ SO, const float* __restrict__ rmax,
    const float* __restrict__ rinv, float* __restrict__ out) {
  __shared__ float as[16][68], bs[16][68];
  const int b = blockIdx.z;
  const int n0 = blockIdx.x * 64, d0 = blockIdx.y * 64;
  const int t = threadIdx.x, tx = t & 15, ty = t >> 4;
  const float* Lb = L + (size_t)b * NT * ESN;
  const float* Sb = SO + (size_t)b * ESN * DD;
  const int ak = t & 15, ar = t >> 4;
  const int bc = t & 63, bk = t >> 6;
  float rm[4];
#pragma unroll
  for (int j = 0; j < 4; ++j) rm[j] = rmax[b * NT + n0 + ar + 16 * j];
  float acc[4][4] = {};
  for (int c0 = 0; c0 < ESN; c0 += 16) {
#pragma unroll
    for (int j = 0; j < 4; ++j)
      as[ak][ar + 16 * j] = expf(Lb[(size_t)(n0 + ar + 16 * j) * ESN + c0 + ak] - rm[j]);
#pragma unroll
    for (int j = 0; j < 4; ++j)
      bs[bk + 4 * j][bc] = Sb[(size_t)(c0 + bk + 4 * j) * DD + d0 + bc];
    __syncthreads();
    tile_fma(as, bs, acc, tx, ty);
    __syncthreads();
  }
#pragma unroll
  for (int i = 0; i < 4; ++i) {
    const int n = n0 + ty * 4 + i;
    const float ri = rinv[b * NT + n];
#pragma unroll
    for (int j = 0; j < 4; ++j)
      out[((size_t)b * SEQ + 1 + n) * DD + d0 + tx * 4 + j] = acc[i][j] * ri;
  }
}

// -------- deterministic metric reduction --------
__global__ __launch_bounds__(256) void k_metrics(const float* __restrict__ t_r2,
    const float* __restrict__ t_dr, const float* __restrict__ t_rs2,
    const float* __restrict__ t_sd, float* __restrict__ out) {
  __shared__ float sm[256];
  const int tid = threadIdx.x;
  float a = 0.f, b = 0.f, c = 0.f, d = 0.f;
  for (int i = tid; i < BB * NT; i += 256) { a += t_r2[i]; b += t_dr[i]; }
  for (int i = tid; i < BB * ESN; i += 256) { c += t_rs2[i]; d += t_sd[i]; }
  float vals[4] = {a, b, c, d};
  float res[4];
#pragma unroll
  for (int v = 0; v < 4; ++v) {
    sm[tid] = vals[v];
    __syncthreads();
    for (int s = 128; s > 0; s >>= 1) {
      if (tid < s) sm[tid] += sm[tid + s];
      __syncthreads();
    }
    res[v] = sm[0];
    __syncthreads();
  }
  if (tid == 0) {
    out[(size_t)BB * SEQ * DD] = (res[0] - res[1]) / 33538048.0f;      // /(b*n*(n-1))
    out[(size_t)BB * SEQ * DD + 1] = (res[2] - res[3]) / 33538048.0f;  // /(b*e*s*(es-1))
  }
}

extern "C" void kernel_launch(void* const* d_in, const int* in_sizes, int n_in,
                              void* d_out, int out_size, void* d_ws, size_t ws_size,
                              hipStream_t stream) {
  const float* x      = (const float*)d_in[0];
  const float* mu     = (const float*)d_in[1];
  const float* scale  = (const float*)d_in[2];
  const float* cls_w1 = (const float*)d_in[3];
  const float* cls_b1 = (const float*)d_in[4];
  const float* cls_w2 = (const float*)d_in[5];
  const float* cls_b2 = (const float*)d_in[6];
  const float* w1     = (const float*)d_in[7];
  const float* b1     = (const float*)d_in[8];
  const float* w2     = (const float*)d_in[9];
  const float* b2     = (const float*)d_in[10];
  float* out = (float*)d_out;

  float* wsp = (float*)d_ws;
  size_t o = 0;
  float* Lb   = wsp + o; o += (size_t)BB * NT * ESN;   // 33,554,432  logits
  float* SI   = wsp + o; o += (size_t)BB * ESN * DD;   // 16,777,216  slot_in (aliased by SO)
  float* H1   = wsp + o; o += (size_t)BB * EE * SS * HH; // 8,388,608 hidden
  float* SO   = SI;                                     // slot_out aliases slot_in (dead by then)
  float* rmax = wsp + o; o += BB * NT;
  float* rinv = wsp + o; o += BB * NT;
  float* cmax = wsp + o; o += BB * ESN;
  float* cinv = wsp + o; o += BB * ESN;
  float* xnf  = wsp + o; o += BB * NT;
  float* munf = wsp + o; o += ESN;
  float* t_r2 = wsp + o; o += BB * NT;
  float* t_dr = wsp + o; o += BB * NT;
  float* t_rs2= wsp + o; o += BB * ESN;
  float* t_sd = wsp + o; o += BB * ESN;
  float* pm   = wsp + o; o += (size_t)NCH * BB * ESN;
  float* ps   = wsp + o; o += (size_t)NCH * BB * ESN;
  float* pq   = wsp + o; o += (size_t)NCH * BB * ESN;
  float* clsh = wsp + o; o += BB * HH;
  // total ~59.6M floats ~= 239 MB of ws

  k_clsA<<<dim3(BB * HH / 4), 256, 0, stream>>>(x, cls_w1, cls_b1, clsh);
  k_clsB<<<dim3(BB * DD / 4), 256, 0, stream>>>(clsh, cls_w2, cls_b2, out);
  k_xnf<<<dim3(BB * NT / 4), 256, 0, stream>>>(x, xnf);
  k_munf<<<dim3(ESN / 256), 256, 0, stream>>>(mu, scale, munf);
  k_logits<<<dim3(NT / 64, ESN / 64, BB), 256, 0, stream>>>(x, mu, xnf, munf, Lb);
  k_rowstats<<<dim3(BB * NT / 4), 256, 0, stream>>>(Lb, rmax, rinv, t_r2, t_dr);
  k_colpart<<<dim3(BB, ESN / 256, NCH), 256, 0, stream>>>(Lb, pm, ps, pq);
  k_colmerge<<<dim3(BB * ESN / 256), 256, 0, stream>>>(pm, ps, pq, cmax, cinv, t_rs2, t_sd);
  k_slot_in<<<dim3(ESN / 64, DD / 64, BB), 256, 0, stream>>>(Lb, x, cmax, cinv, SI);
  k_ffn1<<<dim3(SS / 64, HH / 64, BB * EE), 256, 0, stream>>>(SI, w1, b1, H1);
  k_ffn2<<<dim3(SS / 64, DD / 64, BB * EE), 256, 0, stream>>>(H1, w2, b2, SO);
  k_img<<<dim3(NT / 64, DD / 64, BB), 256, 0, stream>>>(Lb, SO, rmax, rinv, out);
  k_metrics<<<1, 256, 0, stream>>>(t_r2, t_dr, t_rs2, t_sd, out);
}

// Round 2
// 665.804 us; speedup vs baseline: 5.6111x; 5.6111x over previous
//
#include <hip/hip_runtime.h>
#include <math.h>

// Shapes (fixed)
#define BB 8
#define SEQ 2049
#define NT 2048
#define DD 1024
#define EE 8
#define SS 256
#define ESN 2048
#define HH 512
#define NCH 16

typedef __bf16 bf16x8 __attribute__((ext_vector_type(8)));
typedef float f32x4 __attribute__((ext_vector_type(4)));

__device__ __forceinline__ float gelu_f(float v) {
  return 0.5f * v * (1.0f + erff(v * 0.70710678118654752440f));
}
__device__ __forceinline__ float wave_sum(float v) {
#pragma unroll
  for (int off = 1; off < 64; off <<= 1) v += __shfl_xor(v, off);
  return v;
}
__device__ __forceinline__ unsigned short f2bf(float f) {
  unsigned int u = __float_as_uint(f);
  u = (u + 0x7fffu + ((u >> 16) & 1u)) >> 16;
  return (unsigned short)u;
}
__device__ __forceinline__ float bf2f(unsigned short h) {
  return __uint_as_float(((unsigned int)h) << 16);
}

// async 16B/lane global->LDS stage; lbase is wave-uniform, HW adds lane*16.
__device__ __forceinline__ void stage16(const unsigned short* g, unsigned short* lbase, int lane) {
#if __has_builtin(__builtin_amdgcn_global_load_lds)
  __builtin_amdgcn_global_load_lds((const __attribute__((address_space(1))) void*)g,
                                   (__attribute__((address_space(3))) void*)lbase, 16, 0, 0);
#else
  *(int4*)(lbase + lane * 8) = *(const int4*)g;
#endif
}

// ---- bf16 gemm_bt core: C[128m x 128n] = A[m][k] * B[n][k]^T, K%32==0 ----
// 256 threads = 4 waves (2x2 of 64x64). LDS tiles [128][32] bf16 linear.
__device__ __forceinline__ void gemm_core(const unsigned short* __restrict__ A,
                                          const unsigned short* __restrict__ B,
                                          int K, unsigned short* As, unsigned short* Bs,
                                          f32x4 acc[4][4]) {
  const int t = threadIdx.x;
  const int lane = t & 63, wave = t >> 6;
  const int srow = t >> 2, scol = (t & 3) * 8;
  const int fr = lane & 15, fk = (lane >> 4) * 8;
  const int wm = (wave >> 1) * 64, wn = (wave & 1) * 64;
  const unsigned short* a0 = A + (size_t)srow * K + scol;
  const unsigned short* a1 = A + (size_t)(srow + 64) * K + scol;
  const unsigned short* b0 = B + (size_t)srow * K + scol;
  const unsigned short* b1 = B + (size_t)(srow + 64) * K + scol;
  unsigned short* lA0 = As + wave * 512;
  unsigned short* lA1 = As + 2048 + wave * 512;
  unsigned short* lB0 = Bs + wave * 512;
  unsigned short* lB1 = Bs + 2048 + wave * 512;
  for (int k0 = 0; k0 < K; k0 += 32) {
    stage16(a0 + k0, lA0, lane);
    stage16(a1 + k0, lA1, lane);
    stage16(b0 + k0, lB0, lane);
    stage16(b1 + k0, lB1, lane);
    __syncthreads();  // drains vmcnt: staged tiles visible
    bf16x8 af[4], bfr[4];
#pragma unroll
    for (int i = 0; i < 4; ++i)
      af[i] = *(const bf16x8*)(As + (wm + i * 16 + fr) * 32 + fk);
#pragma unroll
    for (int j = 0; j < 4; ++j)
      bfr[j] = *(const bf16x8*)(Bs + (wn + j * 16 + fr) * 32 + fk);
#pragma unroll
    for (int i = 0; i < 4; ++i)
#pragma unroll
      for (int j = 0; j < 4; ++j)
        acc[i][j] = __builtin_amdgcn_mfma_f32_16x16x32_bf16(af[i], bfr[j], acc[i][j], 0, 0, 0);
    __syncthreads();  // all reads done before next stage overwrites
  }
}

#define GEMM_PRE()                                        \
  __shared__ unsigned short As[4096], Bs[4096];           \
  f32x4 acc[4][4];                                        \
  _Pragma("unroll") for (int i = 0; i < 4; ++i)           \
  _Pragma("unroll") for (int j = 0; j < 4; ++j)           \
  _Pragma("unroll") for (int r = 0; r < 4; ++r) acc[i][j][r] = 0.f;

#define GEMM_EPI_VARS()                                   \
  const int lane = threadIdx.x & 63, wave = threadIdx.x >> 6; \
  const int wm = (wave >> 1) * 64, wn = (wave & 1) * 64;

// logits -> E = bf16(exp(logit))
__global__ __launch_bounds__(256) void k_logits_mfma(const unsigned short* __restrict__ Xb,
    const unsigned short* __restrict__ MT, unsigned short* __restrict__ E16) {
  GEMM_PRE();
  const int b = blockIdx.z, m0 = blockIdx.x * 128, n0 = blockIdx.y * 128;
  gemm_core(Xb + ((size_t)b * NT + m0) * DD, MT + (size_t)n0 * DD, DD, As, Bs, acc);
  GEMM_EPI_VARS();
  unsigned short* o = E16 + (size_t)b * NT * ESN;
#pragma unroll
  for (int i = 0; i < 4; ++i)
#pragma unroll
    for (int j = 0; j < 4; ++j) {
      const int gm = m0 + wm + i * 16 + ((lane >> 4) << 2);
      const int gn = n0 + wn + j * 16 + (lane & 15);
#pragma unroll
      for (int r = 0; r < 4; ++r)
        o[(size_t)(gm + r) * ESN + gn] = f2bf(expf(acc[i][j][r]));
    }
}

// slot_in: SI[c][d] = (sum_n E^T[c][n] XT^T...)*cinv[c]
__global__ __launch_bounds__(256) void k_slotin_mfma(const unsigned short* __restrict__ ET,
    const unsigned short* __restrict__ XT, const float* __restrict__ cinv,
    unsigned short* __restrict__ SI) {
  GEMM_PRE();
  const int b = blockIdx.z, m0 = blockIdx.x * 128, n0 = blockIdx.y * 128;
  gemm_core(ET + ((size_t)b * ESN + m0) * NT, XT + ((size_t)b * DD + n0) * NT, NT, As, Bs, acc);
  GEMM_EPI_VARS();
#pragma unroll
  for (int i = 0; i < 4; ++i)
#pragma unroll
    for (int j = 0; j < 4; ++j) {
      const int gm = m0 + wm + i * 16 + ((lane >> 4) << 2);
      const int gn = n0 + wn + j * 16 + (lane & 15);
#pragma unroll
      for (int r = 0; r < 4; ++r) {
        const float ci = cinv[b * ESN + gm + r];
        SI[((size_t)b * ESN + gm + r) * DD + gn] = f2bf(acc[i][j][r] * ci);
      }
    }
}

__global__ __launch_bounds__(256) void k_ffn1_mfma(const unsigned short* __restrict__ SI,
    const unsigned short* __restrict__ w1b, const float* __restrict__ b1,
    unsigned short* __restrict__ H1) {
  GEMM_PRE();
  const int z = blockIdx.z, b = z >> 3, e = z & 7;
  const int m0 = blockIdx.x * 128, n0 = blockIdx.y * 128;
  gemm_core(SI + ((size_t)b * ESN + e * SS + m0) * DD, w1b + ((size_t)e * HH + n0) * DD,
            DD, As, Bs, acc);
  GEMM_EPI_VARS();
#pragma unroll
  for (int i = 0; i < 4; ++i)
#pragma unroll
    for (int j = 0; j < 4; ++j) {
      const int gm = m0 + wm + i * 16 + ((lane >> 4) << 2);
      const int gn = n0 + wn + j * 16 + (lane & 15);
      const float bias = b1[e * HH + gn];
#pragma unroll
      for (int r = 0; r < 4; ++r)
        H1[((size_t)(b * EE + e) * SS + gm + r) * HH + gn] = f2bf(gelu_f(acc[i][j][r] + bias));
    }
}

__global__ __launch_bounds__(256) void k_ffn2_mfma(const unsigned short* __restrict__ H1,
    const unsigned short* __restrict__ w2b, const float* __restrict__ b2,
    unsigned short* __restrict__ SO) {
  GEMM_PRE();
  const int z = blockIdx.z, b = z >> 3, e = z & 7;
  const int m0 = blockIdx.x * 128, n0 = blockIdx.y * 128;
  gemm_core(H1 + ((size_t)(b * EE + e) * SS + m0) * HH, w2b + ((size_t)e * DD + n0) * HH,
            HH, As, Bs, acc);
  GEMM_EPI_VARS();
#pragma unroll
  for (int i = 0; i < 4; ++i)
#pragma unroll
    for (int j = 0; j < 4; ++j) {
      const int gm = m0 + wm + i * 16 + ((lane >> 4) << 2);
      const int gn = n0 + wn + j * 16 + (lane & 15);
      const float bias = b2[e * DD + gn];
#pragma unroll
      for (int r = 0; r < 4; ++r)
        SO[((size_t)b * ESN + e * SS + gm + r) * DD + gn] = f2bf(acc[i][j][r] + bias);
    }
}

__global__ __launch_bounds__(256) void k_img_mfma(const unsigned short* __restrict__ E16,
    const unsigned short* __restrict__ SOT, const float* __restrict__ rinv,
    float* __restrict__ out) {
  GEMM_PRE();
  const int b = blockIdx.z, m0 = blockIdx.x * 128, n0 = blockIdx.y * 128;
  gemm_core(E16 + ((size_t)b * NT + m0) * ESN, SOT + ((size_t)b * DD + n0) * ESN,
            ESN, As, Bs, acc);
  GEMM_EPI_VARS();
#pragma unroll
  for (int i = 0; i < 4; ++i)
#pragma unroll
    for (int j = 0; j < 4; ++j) {
      const int gm = m0 + wm + i * 16 + ((lane >> 4) << 2);
      const int gn = n0 + wn + j * 16 + (lane & 15);
#pragma unroll
      for (int r = 0; r < 4; ++r)
        out[((size_t)b * SEQ + 1 + gm + r) * DD + gn] = acc[i][j][r] * rinv[b * NT + gm + r];
    }
}

// -------- packing / transpose --------
__global__ __launch_bounds__(256) void k_xnf(const float* __restrict__ x, float* __restrict__ xnf) {
  const int wid = blockIdx.x * 4 + (threadIdx.x >> 6);
  const int lane = threadIdx.x & 63;
  const int b = wid >> 11;
  const float* row = x + ((size_t)b * SEQ + 1 + (wid & (NT - 1))) * DD;
  float s = 0.f;
#pragma unroll
  for (int k = 0; k < DD / 64; ++k) { const float v = row[lane + k * 64]; s = fmaf(v, v, s); }
  s = wave_sum(s);
  if (lane == 0) xnf[wid] = 1.0f / fmaxf(sqrtf(s), 1e-12f);
}

__global__ __launch_bounds__(256) void k_munf(const float* __restrict__ mu,
    const float* __restrict__ scale, float* __restrict__ munf) {
  __shared__ float part[4][64];
  const int c0 = blockIdx.x * 64;
  const int ci = threadIdx.x & 63, dg = threadIdx.x >> 6;
  float s = 0.f;
  for (int d = dg; d < DD; d += 4) { const float v = mu[(size_t)d * ESN + c0 + ci]; s = fmaf(v, v, s); }
  part[dg][ci] = s;
  __syncthreads();
  if (threadIdx.x < 64) {
    const float t = part[0][ci] + part[1][ci] + part[2][ci] + part[3][ci];
    munf[c0 + ci] = scale[0] / fmaxf(sqrtf(t), 1e-12f);
  }
}

__global__ __launch_bounds__(256) void k_pack_x(const float* __restrict__ x,
    const float* __restrict__ xnf, unsigned short* __restrict__ Xb,
    unsigned short* __restrict__ XT) {
  __shared__ unsigned short tile[64][72];
  const int b = blockIdx.z, n0 = blockIdx.x * 64, d0 = blockIdx.y * 64;
  const int t = threadIdx.x, tr = t >> 2, tc = (t & 3) * 16;
  const float* s = x + ((size_t)b * SEQ + 1 + n0 + tr) * DD + d0 + tc;
  const float xs = xnf[b * NT + n0 + tr];
  unsigned short tmp[16];
#pragma unroll
  for (int j = 0; j < 16; j += 4) {
    float4 v = *(const float4*)(s + j);
    tmp[j] = f2bf(v.x * xs); tmp[j + 1] = f2bf(v.y * xs);
    tmp[j + 2] = f2bf(v.z * xs); tmp[j + 3] = f2bf(v.w * xs);
  }
  *(int4*)&tile[tr][tc] = *(int4*)tmp;
  *(int4*)&tile[tr][tc + 8] = *(int4*)(tmp + 8);
  unsigned short* xb = Xb + ((size_t)b * NT + n0 + tr) * DD + d0 + tc;
  *(int4*)xb = *(int4*)tmp;
  *(int4*)(xb + 8) = *(int4*)(tmp + 8);
  __syncthreads();
  unsigned short* d = XT + ((size_t)b * DD + d0 + tr) * NT + n0 + tc;
#pragma unroll
  for (int j = 0; j < 16; ++j) tmp[j] = tile[tc + j][tr];
  *(int4*)d = *(int4*)tmp;
  *(int4*)(d + 8) = *(int4*)(tmp + 8);
}

__global__ __launch_bounds__(256) void k_pack_mu(const float* __restrict__ mu,
    const float* __restrict__ munf, unsigned short* __restrict__ MT) {
  __shared__ unsigned short tile[64][72];
  const int d0 = blockIdx.x * 64, c0 = blockIdx.y * 64;
  const int t = threadIdx.x, tr = t >> 2, tc = (t & 3) * 16;
  const float* s = mu + (size_t)(d0 + tr) * ESN + c0 + tc;
  unsigned short tmp[16];
#pragma unroll
  for (int j = 0; j < 16; j += 4) {
    float4 v = *(const float4*)(s + j);
    tmp[j] = f2bf(v.x * munf[c0 + tc + j]);
    tmp[j + 1] = f2bf(v.y * munf[c0 + tc + j + 1]);
    tmp[j + 2] = f2bf(v.z * munf[c0 + tc + j + 2]);
    tmp[j + 3] = f2bf(v.w * munf[c0 + tc + j + 3]);
  }
  *(int4*)&tile[tr][tc] = *(int4*)tmp;
  *(int4*)&tile[tr][tc + 8] = *(int4*)(tmp + 8);
  __syncthreads();
  unsigned short* d = MT + (size_t)(c0 + tr) * DD + d0 + tc;
#pragma unroll
  for (int j = 0; j < 16; ++j) tmp[j] = tile[tc + j][tr];
  *(int4*)d = *(int4*)tmp;
  *(int4*)(d + 8) = *(int4*)(tmp + 8);
}

__global__ __launch_bounds__(256) void k_trans16(const unsigned short* __restrict__ src,
    unsigned short* __restrict__ dst, int R, int C) {
  __shared__ unsigned short tile[64][72];
  const size_t bo = (size_t)blockIdx.z * R * C;
  const int r0 = blockIdx.x * 64, c0 = blockIdx.y * 64;
  const int t = threadIdx.x, tr = t >> 2, tc = (t & 3) * 16;
  const unsigned short* s = src + bo + (size_t)(r0 + tr) * C + c0 + tc;
  *(int4*)&tile[tr][tc] = *(const int4*)s;
  *(int4*)&tile[tr][tc + 8] = *(const int4*)(s + 8);
  __syncthreads();
  unsigned short* d = dst + bo + (size_t)(c0 + tr) * R + r0 + tc;
  unsigned short tmp[16];
#pragma unroll
  for (int j = 0; j < 16; ++j) tmp[j] = tile[tc + j][tr];
  *(int4*)d = *(int4*)tmp;
  *(int4*)(d + 8) = *(int4*)(tmp + 8);
}

__global__ __launch_bounds__(256) void k_packw(const float* __restrict__ w,
    unsigned short* __restrict__ o, int n4) {
  const int i = blockIdx.x * 256 + threadIdx.x;
  if (i < n4) {
    float4 v = ((const float4*)w)[i];
    ushort4 u;
    u.x = f2bf(v.x); u.y = f2bf(v.y); u.z = f2bf(v.z); u.w = f2bf(v.w);
    ((ushort4*)o)[i] = u;
  }
}

// -------- softmax stats from E --------
__global__ __launch_bounds__(256) void k_rowstats_e(const unsigned short* __restrict__ E,
    float* __restrict__ rinv, float* __restrict__ t_r2, float* __restrict__ t_dr) {
  const int wid = blockIdx.x * 4 + (threadIdx.x >> 6);
  const int lane = threadIdx.x & 63;
  const int n = wid & (NT - 1);
  const unsigned short* row = E + (size_t)wid * ESN;
  float s1 = 0.f, s2 = 0.f;
#pragma unroll
  for (int it = 0; it < 4; ++it) {
    int4 v = *(const int4*)(row + it * 512 + lane * 8);
    const unsigned short* u = (const unsigned short*)&v;
#pragma unroll
    for (int j = 0; j < 8; ++j) { const float e = bf2f(u[j]); s1 += e; s2 = fmaf(e, e, s2); }
  }
  s1 = wave_sum(s1); s2 = wave_sum(s2);
  if (lane == 0) {
    const float ri = 1.0f / s1;
    rinv[wid] = ri;
    const float r2 = 1.0f / (s2 * ri * ri + 1e-9f);
    t_r2[wid] = r2;
    t_dr[wid] = bf2f(row[n]) * ri * r2;
  }
}

__global__ __launch_bounds__(256) void k_colpart_e(const unsigned short* __restrict__ E,
    float* __restrict__ ps2, float* __restrict__ pq2) {
  const int b = blockIdx.x, cb = blockIdx.y, nch = blockIdx.z;
  const int c = cb * 256 + threadIdx.x;
  const unsigned short* base = E + ((size_t)b * NT + nch * (NT / NCH)) * ESN + c;
  float s = 0.f, q = 0.f;
  for (int i = 0; i < NT / NCH; ++i) {
    const float e = bf2f(base[(size_t)i * ESN]);
    s += e; q = fmaf(e, e, q);
  }
  const int idx = (nch * BB + b) * ESN + c;
  ps2[idx] = s; pq2[idx] = q;
}

__global__ __launch_bounds__(256) void k_colmerge_e(const float* __restrict__ ps2,
    const float* __restrict__ pq2, float* __restrict__ cinv,
    float* __restrict__ t_rs2, float* __restrict__ t_sd) {
  const int gid = blockIdx.x * 256 + threadIdx.x;
  float s = 0.f, q = 0.f;
#pragma unroll
  for (int k = 0; k < NCH; ++k) {
    s += ps2[k * (BB * ESN) + gid];
    q += pq2[k * (BB * ESN) + gid];
  }
  const float ci = 1.0f / s;
  cinv[gid] = ci;
  const float rs2 = 1.0f / (q * ci * ci + 1e-9f);
  t_rs2[gid] = rs2;
  const int c = gid & (ESN - 1);
  t_sd[gid] = ((c % 257) == 0) ? rs2 : 0.f;
}

// -------- cls path (f32, tiny) --------
__global__ __launch_bounds__(256) void k_clsA(const float* __restrict__ x,
    const float* __restrict__ w1, const float* __restrict__ b1, float* __restrict__ clsh) {
  const int wid = blockIdx.x * 4 + (threadIdx.x >> 6);
  const int lane = threadIdx.x & 63;
  const int b = wid >> 9, h = wid & (HH - 1);
  const float* xr = x + (size_t)b * SEQ * DD;
  const float* wr = w1 + (size_t)h * DD;
  float s = 0.f;
#pragma unroll
  for (int k = 0; k < DD / 64; ++k) s = fmaf(xr[lane + k * 64], wr[lane + k * 64], s);
  s = wave_sum(s);
  if (lane == 0) clsh[wid] = gelu_f(s + b1[h]);
}

__global__ __launch_bounds__(256) void k_clsB(const float* __restrict__ clsh,
    const float* __restrict__ w2, const float* __restrict__ b2, float* __restrict__ out) {
  const int wid = blockIdx.x * 4 + (threadIdx.x >> 6);
  const int lane = threadIdx.x & 63;
  const int b = wid >> 10, d = wid & (DD - 1);
  const float* hr = clsh + (size_t)b * HH;
  const float* wr = w2 + (size_t)d * HH;
  float s = 0.f;
#pragma unroll
  for (int k = 0; k < HH / 64; ++k) s = fmaf(hr[lane + k * 64], wr[lane + k * 64], s);
  s = wave_sum(s);
  if (lane == 0) out[(size_t)b * SEQ * DD + d] = s + b2[d];
}

__global__ __launch_bounds__(256) void k_metrics(const float* __restrict__ t_r2,
    const float* __restrict__ t_dr, const float* __restrict__ t_rs2,
    const float* __restrict__ t_sd, float* __restrict__ out) {
  __shared__ float sm[256];
  const int tid = threadIdx.x;
  float a = 0.f, b = 0.f, c = 0.f, d = 0.f;
  for (int i = tid; i < BB * NT; i += 256) { a += t_r2[i]; b += t_dr[i]; }
  for (int i = tid; i < BB * ESN; i += 256) { c += t_rs2[i]; d += t_sd[i]; }
  float vals[4] = {a, b, c, d};
  float res[4];
#pragma unroll
  for (int v = 0; v < 4; ++v) {
    sm[tid] = vals[v];
    __syncthreads();
    for (int s = 128; s > 0; s >>= 1) {
      if (tid < s) sm[tid] += sm[tid + s];
      __syncthreads();
    }
    res[v] = sm[0];
    __syncthreads();
  }
  if (tid == 0) {
    out[(size_t)BB * SEQ * DD] = (res[0] - res[1]) / 33538048.0f;
    out[(size_t)BB * SEQ * DD + 1] = (res[2] - res[3]) / 33538048.0f;
  }
}

extern "C" void kernel_launch(void* const* d_in, const int* in_sizes, int n_in,
                              void* d_out, int out_size, void* d_ws, size_t ws_size,
                              hipStream_t stream) {
  const float* x      = (const float*)d_in[0];
  const float* mu     = (const float*)d_in[1];
  const float* scale  = (const float*)d_in[2];
  const float* cls_w1 = (const float*)d_in[3];
  const float* cls_b1 = (const float*)d_in[4];
  const float* cls_w2 = (const float*)d_in[5];
  const float* cls_b2 = (const float*)d_in[6];
  const float* w1     = (const float*)d_in[7];
  const float* b1     = (const float*)d_in[8];
  const float* w2     = (const float*)d_in[9];
  const float* b2     = (const float*)d_in[10];
  float* out = (float*)d_out;

  char* W = (char*)d_ws;
  unsigned short* XT  = (unsigned short*)(W);                  // 33,554,432 B
  unsigned short* MT  = (unsigned short*)(W + 33554432);       //  4,194,304
  unsigned short* E16 = (unsigned short*)(W + 37748736);       // 67,108,864
  char* REGD = W + 104857600;                                  // 67,108,864 region
  unsigned short* Xb  = (unsigned short*)REGD;                 // dies after logits
  unsigned short* ET  = (unsigned short*)REGD;                 // dies after slot_in
  unsigned short* H1  = (unsigned short*)REGD;                 // 16,777,216
  unsigned short* SOT = (unsigned short*)(REGD + 16777216);    // 33,554,432
  unsigned short* SI  = (unsigned short*)(W + 171966464);      // 33,554,432 (SO aliases)
  unsigned short* SO  = SI;
  unsigned short* w1b = (unsigned short*)(W + 205520896);      //  8,388,608
  unsigned short* w2b = (unsigned short*)(W + 213909504);      //  8,388,608
  float* F = (float*)(W + 222298112);
  float* xnf   = F;
  float* munf  = F + 16384;
  float* rinv  = F + 18432;
  float* t_r2  = F + 34816;
  float* t_dr  = F + 51200;
  float* cinv  = F + 67584;
  float* t_rs2 = F + 83968;
  float* t_sd  = F + 100352;
  float* ps2   = F + 116736;
  float* pq2   = F + 378880;
  float* clsh  = F + 641024;   // total ws ~224.9 MB

  k_xnf<<<dim3(BB * NT / 4), 256, 0, stream>>>(x, xnf);
  k_munf<<<dim3(ESN / 64), 256, 0, stream>>>(mu, scale, munf);
  k_pack_x<<<dim3(NT / 64, DD / 64, BB), 256, 0, stream>>>(x, xnf, Xb, XT);
  k_pack_mu<<<dim3(DD / 64, ESN / 64), 256, 0, stream>>>(mu, munf, MT);
  k_packw<<<dim3(EE * HH * DD / 4 / 256), 256, 0, stream>>>(w1, w1b, EE * HH * DD / 4);
  k_packw<<<dim3(EE * DD * HH / 4 / 256), 256, 0, stream>>>(w2, w2b, EE * DD * HH / 4);
  k_logits_mfma<<<dim3(NT / 128, ESN / 128, BB), 256, 0, stream>>>(Xb, MT, E16);
  k_trans16<<<dim3(NT / 64, ESN / 64, BB), 256, 0, stream>>>(E16, ET, NT, ESN);
  k_rowstats_e<<<dim3(BB * NT / 4), 256, 0, stream>>>(E16, rinv, t_r2, t_dr);
  k_colpart_e<<<dim3(BB, ESN / 256, NCH), 256, 0, stream>>>(E16, ps2, pq2);
  k_colmerge_e<<<dim3(BB * ESN / 256), 256, 0, stream>>>(ps2, pq2, cinv, t_rs2, t_sd);
  k_slotin_mfma<<<dim3(ESN / 128, DD / 128, BB), 256, 0, stream>>>(ET, XT, cinv, SI);
  k_ffn1_mfma<<<dim3(SS / 128, HH / 128, BB * EE), 256, 0, stream>>>(SI, w1b, b1, H1);
  k_ffn2_mfma<<<dim3(SS / 128, DD / 128, BB * EE), 256, 0, stream>>>(H1, w2b, b2, SO);
  k_trans16<<<dim3(ESN / 64, DD / 64, BB), 256, 0, stream>>>(SO, SOT, ESN, DD);
  k_img_mfma<<<dim3(NT / 128, DD / 128, BB), 256, 0, stream>>>(E16, SOT, rinv, out);
  k_clsA<<<dim3(BB * HH / 4), 256, 0, stream>>>(x, cls_w1, cls_b1, clsh);
  k_clsB<<<dim3(BB * DD / 4), 256, 0, stream>>>(clsh, cls_w2, cls_b2, out);
  k_metrics<<<1, 256, 0, stream>>>(t_r2, t_dr, t_rs2, t_sd, out);
}